// Round 6
// baseline (984.591 us; speedup 1.0000x reference)
//
#include <hip/hip_runtime.h>
#include <math.h>

#define TOKENS 65536
#define DMODEL 768
#define HDIM 128
#define CDIM 64
#define NCODE 2048

__device__ __forceinline__ float gelu_exact(float v) {
    return 0.5f * v * (1.0f + erff(v * 0.7071067811865476f));
}

__device__ __forceinline__ void load_lds16(const float* g, float* l) {
    __builtin_amdgcn_global_load_lds(
        (const __attribute__((address_space(1))) void*)g,
        (__attribute__((address_space(3))) void*)l, 16, 0, 0);
}

// ---------------------------------------------------------------------------
// Fused encoder: Z = GELU(X @ W1 + b1) @ W2 + b2
// Grid: TOKENS/64 blocks, 256 threads, 64 tokens/block.
// Phase A: X read direct from global (half-wave broadcast, L1-resident tile;
// LDS staging of X was pure overhead — no cross-wave reuse). W1 staged via
// global_load_lds into a 2-deep pipeline: STAGE(next) issued BEFORE compute
// of current, single barrier per tile so the vmcnt drain hides under ~2000cy
// of FMA (T3-minimum 2-phase schedule).
// LDS: union{Wbuf dbuf 32KB, H1 33.8KB} -> 4 blocks/CU.
// ---------------------------------------------------------------------------
__global__ __launch_bounds__(256) __attribute__((amdgpu_waves_per_eu(4, 4)))
void enc_fused(const float* __restrict__ x, const float* __restrict__ w1,
               const float* __restrict__ b1, const float* __restrict__ w2,
               const float* __restrict__ b2, float* __restrict__ Z)
{
    __shared__ union {
        float Wbuf[2][32][128];   // 2 x 16 KB
        float H1s[64][132];       // 33792 B
    } u;

    const int t = threadIdx.x;
    const int w = t >> 6, l = t & 63;
    const size_t tok0 = (size_t)blockIdx.x * 64;
    const int tg = t >> 5;   // 0..7; this thread's tokens are tg + 8*i
    const int cg = t & 31;   // cols cg*4 .. cg*4+3

    float acc[8][4];
    #pragma unroll
    for (int i = 0; i < 8; ++i)
        #pragma unroll
        for (int j = 0; j < 4; ++j) acc[i][j] = 0.f;

    // per-thread X row bases (8 rows, half-wave-uniform addresses)
    const float* xbase[8];
    #pragma unroll
    for (int i = 0; i < 8; ++i)
        xbase[i] = x + (tok0 + tg + 8 * i) * DMODEL;

    // W1 staging: thread stages 4 x 16B chunks, lane-linear LDS dest
    const int wrow_ = l >> 5;          // + 2*(w*4+j)
    const int wcol_ = 4 * (l & 31);

    #define STAGE_W(buf, k0s)                                              \
        {                                                                  \
            float* dst = &u.Wbuf[buf][0][0];                               \
            _Pragma("unroll")                                              \
            for (int j = 0; j < 4; ++j) {                                  \
                const int chunk = w * 4 + j;                               \
                const int row = chunk * 2 + wrow_;                         \
                load_lds16(w1 + (size_t)((k0s) + row) * HDIM + wcol_,      \
                           dst + chunk * 256);                             \
            }                                                              \
        }

    STAGE_W(0, 0);
    __syncthreads();   // drain vmcnt + sync: Wbuf[0] ready

    for (int tile = 0; tile < 24; ++tile) {
        const int k0 = tile * 32;
        const int cur = tile & 1;
        if (tile + 1 < 24) STAGE_W(cur ^ 1, k0 + 32);   // async, in flight across compute
        const float(*Wc)[128] = u.Wbuf[cur];
        #pragma unroll
        for (int kk = 0; kk < 32; kk += 4) {
            float4 av[8];
            #pragma unroll
            for (int i = 0; i < 8; ++i)
                av[i] = *reinterpret_cast<const float4*>(xbase[i] + k0 + kk);
            float4 bv[4];
            #pragma unroll
            for (int q = 0; q < 4; ++q)
                bv[q] = *reinterpret_cast<const float4*>(&Wc[kk + q][cg * 4]);
            #pragma unroll
            for (int i = 0; i < 8; ++i) {
                acc[i][0] = fmaf(av[i].x, bv[0].x, acc[i][0]);
                acc[i][1] = fmaf(av[i].x, bv[0].y, acc[i][1]);
                acc[i][2] = fmaf(av[i].x, bv[0].z, acc[i][2]);
                acc[i][3] = fmaf(av[i].x, bv[0].w, acc[i][3]);
                acc[i][0] = fmaf(av[i].y, bv[1].x, acc[i][0]);
                acc[i][1] = fmaf(av[i].y, bv[1].y, acc[i][1]);
                acc[i][2] = fmaf(av[i].y, bv[1].z, acc[i][2]);
                acc[i][3] = fmaf(av[i].y, bv[1].w, acc[i][3]);
                acc[i][0] = fmaf(av[i].z, bv[2].x, acc[i][0]);
                acc[i][1] = fmaf(av[i].z, bv[2].y, acc[i][1]);
                acc[i][2] = fmaf(av[i].z, bv[2].z, acc[i][2]);
                acc[i][3] = fmaf(av[i].z, bv[2].w, acc[i][3]);
                acc[i][0] = fmaf(av[i].w, bv[3].x, acc[i][0]);
                acc[i][1] = fmaf(av[i].w, bv[3].y, acc[i][1]);
                acc[i][2] = fmaf(av[i].w, bv[3].z, acc[i][2]);
                acc[i][3] = fmaf(av[i].w, bv[3].w, acc[i][3]);
            }
        }
        __syncthreads();   // readers of Wbuf[cur] done; drains next-tile stage
    }

    // bias + GELU -> H1s (overlays the dead Wbuf region; barrier above covers)
    {
        float4 b1v = *reinterpret_cast<const float4*>(b1 + cg * 4);
        #pragma unroll
        for (int i = 0; i < 8; ++i) {
            float4 h;
            h.x = gelu_exact(acc[i][0] + b1v.x);
            h.y = gelu_exact(acc[i][1] + b1v.y);
            h.z = gelu_exact(acc[i][2] + b1v.z);
            h.w = gelu_exact(acc[i][3] + b1v.w);
            *reinterpret_cast<float4*>(&u.H1s[tg + 8 * i][cg * 4]) = h;
        }
    }
    __syncthreads();

    // phase B: Z = H1 @ W2 + b2 ; W2 read from global (32 KB, L2-hot)
    const int tg2 = t >> 4;   // 0..15; tokens tg2 + 16*i (i<4)
    const int cg2 = t & 15;   // cols cg2*4 .. +3
    const float4* w2_4 = reinterpret_cast<const float4*>(w2);   // 16 f4 per row
    float accB[4][4];
    #pragma unroll
    for (int i = 0; i < 4; ++i)
        #pragma unroll
        for (int j = 0; j < 4; ++j) accB[i][j] = 0.f;

    float4 bvn[4];
    #pragma unroll
    for (int q = 0; q < 4; ++q) bvn[q] = w2_4[(size_t)q * 16 + cg2];

    for (int k = 0; k < HDIM; k += 4) {
        float4 bv[4];
        #pragma unroll
        for (int q = 0; q < 4; ++q) bv[q] = bvn[q];
        if (k + 4 < HDIM) {
            #pragma unroll
            for (int q = 0; q < 4; ++q)
                bvn[q] = w2_4[(size_t)(k + 4 + q) * 16 + cg2];
        }
        float4 av[4];
        #pragma unroll
        for (int i = 0; i < 4; ++i)
            av[i] = *reinterpret_cast<const float4*>(&u.H1s[tg2 + 16 * i][k]);
        #pragma unroll
        for (int i = 0; i < 4; ++i) {
            accB[i][0] = fmaf(av[i].x, bv[0].x, accB[i][0]);
            accB[i][1] = fmaf(av[i].x, bv[0].y, accB[i][1]);
            accB[i][2] = fmaf(av[i].x, bv[0].z, accB[i][2]);
            accB[i][3] = fmaf(av[i].x, bv[0].w, accB[i][3]);
            accB[i][0] = fmaf(av[i].y, bv[1].x, accB[i][0]);
            accB[i][1] = fmaf(av[i].y, bv[1].y, accB[i][1]);
            accB[i][2] = fmaf(av[i].y, bv[1].z, accB[i][2]);
            accB[i][3] = fmaf(av[i].y, bv[1].w, accB[i][3]);
            accB[i][0] = fmaf(av[i].z, bv[2].x, accB[i][0]);
            accB[i][1] = fmaf(av[i].z, bv[2].y, accB[i][1]);
            accB[i][2] = fmaf(av[i].z, bv[2].z, accB[i][2]);
            accB[i][3] = fmaf(av[i].z, bv[2].w, accB[i][3]);
            accB[i][0] = fmaf(av[i].w, bv[3].x, accB[i][0]);
            accB[i][1] = fmaf(av[i].w, bv[3].y, accB[i][1]);
            accB[i][2] = fmaf(av[i].w, bv[3].z, accB[i][2]);
            accB[i][3] = fmaf(av[i].w, bv[3].w, accB[i][3]);
        }
    }
    {
        float4 b2v = *reinterpret_cast<const float4*>(b2 + cg2 * 4);
        #pragma unroll
        for (int i = 0; i < 4; ++i) {
            float4 o;
            o.x = accB[i][0] + b2v.x;
            o.y = accB[i][1] + b2v.y;
            o.z = accB[i][2] + b2v.z;
            o.w = accB[i][3] + b2v.w;
            *reinterpret_cast<float4*>(Z + (tok0 + tg2 + 16 * i) * CDIM + cg2 * 4) = o;
        }
    }
    #undef STAGE_W
}

// ---------------------------------------------------------------------------
// VQ: argmin over 2048 codes + loss partial sums.  (unchanged this round —
// no counters for it yet; enc fix should surface it in top-5 next bench)
// ---------------------------------------------------------------------------
__global__ __launch_bounds__(256)
void vq_kernel(const float* __restrict__ Z, const float* __restrict__ cb,
               const float* __restrict__ cnorm, int* __restrict__ idx_out,
               float* __restrict__ idxf_out, float* __restrict__ loss_accum)
{
    __shared__ float Zs[64][68];     // 17.4 KB, padded
    __shared__ float CsT[64][128];   // 32 KB, [k][code]
    __shared__ float tgsum[8];

    const int t = threadIdx.x;
    const size_t tok0 = (size_t)blockIdx.x * 64;
    const int tg = t >> 5, cg = t & 31;
    const int lc = t >> 1, lh = t & 1;

    // load Z tile + prologue codebook tile 0 into regs
    {
        int ltok = t >> 2, lq = t & 3;
        const float4* src = reinterpret_cast<const float4*>(Z + (tok0 + ltok) * CDIM + lq * 16);
        float4* dst = reinterpret_cast<float4*>(&Zs[ltok][lq * 16]);
        dst[0] = src[0]; dst[1] = src[1]; dst[2] = src[2]; dst[3] = src[3];
    }
    float4 cv[8];
    {
        const float4* src = reinterpret_cast<const float4*>(cb + (size_t)lc * CDIM + lh * 32);
        #pragma unroll
        for (int i = 0; i < 8; ++i) cv[i] = src[i];
    }
    __syncthreads();

    // znorm for this thread's 8 tokens (rows tg + 8*i), butterfly over 32 lanes
    float zn[8];
    {
        #pragma unroll
        for (int i = 0; i < 8; ++i) {
            float a = Zs[tg + 8 * i][cg * 2];
            float b = Zs[tg + 8 * i][cg * 2 + 1];
            zn[i] = fmaf(a, a, b * b);
        }
        #pragma unroll
        for (int m = 16; m >= 1; m >>= 1)
            #pragma unroll
            for (int i = 0; i < 8; ++i) zn[i] += __shfl_xor(zn[i], m, 32);
    }

    float minv[8]; int mini[8];
    #pragma unroll
    for (int i = 0; i < 8; ++i) { minv[i] = INFINITY; mini[i] = 0; }

    for (int tile = 0; tile < 16; ++tile) {
        const int code0 = tile * 128;
        __syncthreads();
        // scatter staged regs -> CsT[k][code] (transposed)
        #pragma unroll
        for (int i = 0; i < 8; ++i) {
            int k = lh * 32 + i * 4;
            CsT[k + 0][lc] = cv[i].x;
            CsT[k + 1][lc] = cv[i].y;
            CsT[k + 2][lc] = cv[i].z;
            CsT[k + 3][lc] = cv[i].w;
        }
        __syncthreads();
        // prefetch next tile to regs
        if (tile + 1 < 16) {
            const float4* src = reinterpret_cast<const float4*>(
                cb + (size_t)(code0 + 128 + lc) * CDIM + lh * 32);
            #pragma unroll
            for (int i = 0; i < 8; ++i) cv[i] = src[i];
        }

        float dot[8][4];
        #pragma unroll
        for (int i = 0; i < 8; ++i)
            #pragma unroll
            for (int j = 0; j < 4; ++j) dot[i][j] = 0.f;

        #pragma unroll
        for (int k = 0; k < CDIM; k += 4) {
            float4 av[8];
            #pragma unroll
            for (int i = 0; i < 8; ++i)
                av[i] = *reinterpret_cast<const float4*>(&Zs[tg + 8 * i][k]);
            float4 bv[4];
            #pragma unroll
            for (int q = 0; q < 4; ++q)
                bv[q] = *reinterpret_cast<const float4*>(&CsT[k + q][cg * 4]);
            #pragma unroll
            for (int i = 0; i < 8; ++i) {
                dot[i][0] = fmaf(av[i].x, bv[0].x, dot[i][0]);
                dot[i][1] = fmaf(av[i].x, bv[0].y, dot[i][1]);
                dot[i][2] = fmaf(av[i].x, bv[0].z, dot[i][2]);
                dot[i][3] = fmaf(av[i].x, bv[0].w, dot[i][3]);
                dot[i][0] = fmaf(av[i].y, bv[1].x, dot[i][0]);
                dot[i][1] = fmaf(av[i].y, bv[1].y, dot[i][1]);
                dot[i][2] = fmaf(av[i].y, bv[1].z, dot[i][2]);
                dot[i][3] = fmaf(av[i].y, bv[1].w, dot[i][3]);
                dot[i][0] = fmaf(av[i].z, bv[2].x, dot[i][0]);
                dot[i][1] = fmaf(av[i].z, bv[2].y, dot[i][1]);
                dot[i][2] = fmaf(av[i].z, bv[2].z, dot[i][2]);
                dot[i][3] = fmaf(av[i].z, bv[2].w, dot[i][3]);
                dot[i][0] = fmaf(av[i].w, bv[3].x, dot[i][0]);
                dot[i][1] = fmaf(av[i].w, bv[3].y, dot[i][1]);
                dot[i][2] = fmaf(av[i].w, bv[3].z, dot[i][2]);
                dot[i][3] = fmaf(av[i].w, bv[3].w, dot[i][3]);
            }
        }
        // score = (znorm + cnorm) - 2*dot  (reference expression order)
        #pragma unroll
        for (int j = 0; j < 4; ++j) {
            int ci = code0 + cg * 4 + j;
            float cn = cnorm[ci];
            #pragma unroll
            for (int i = 0; i < 8; ++i) {
                float s = (zn[i] + cn) - 2.f * dot[i][j];
                if (s < minv[i]) { minv[i] = s; mini[i] = ci; }
            }
        }
    }

    // reduce argmin across 32 lanes of each token group (first-min tie-break)
    #pragma unroll
    for (int i = 0; i < 8; ++i) {
        float v = minv[i]; int ci = mini[i];
        #pragma unroll
        for (int m = 16; m >= 1; m >>= 1) {
            float ov = __shfl_xor(v, m, 32);
            int oi = __shfl_xor(ci, m, 32);
            if (ov < v || (ov == v && oi < ci)) { v = ov; ci = oi; }
        }
        minv[i] = v; mini[i] = ci;
    }

    if (cg == 0) {
        float s = 0.f;
        #pragma unroll
        for (int i = 0; i < 8; ++i) {
            size_t tok = tok0 + tg + 8 * i;
            idx_out[tok] = mini[i];
            idxf_out[tok] = (float)mini[i];
            s += minv[i];          // minv == ||z_q - z||^2
        }
        tgsum[tg] = s;
    }
    __syncthreads();
    if (t == 0) {
        float s = 0.f;
        #pragma unroll
        for (int i = 0; i < 8; ++i) s += tgsum[i];
        atomicAdd(loss_accum, s);
    }
}

// ---------------------------------------------------------------------------
// decoder stage 1 over codebook: T1 = GELU(cb @ dec_w1 + b1)   (2048 x 128)
// also computes cnorm[c] = ||cb[c]||^2 (fused)
// ---------------------------------------------------------------------------
__global__ __launch_bounds__(256)
void dec1_kernel(const float* __restrict__ cb, const float* __restrict__ w1,
                 const float* __restrict__ b1, float* __restrict__ T1,
                 float* __restrict__ cnorm)
{
    __shared__ float Cs[64][68];   // padded
    __shared__ float Ws[64][128];

    const int t = threadIdx.x;
    const int c0 = blockIdx.x * 64;
    {
        int lc = t >> 2, lq = t & 3;
        const float4* src = reinterpret_cast<const float4*>(cb + (size_t)(c0 + lc) * CDIM + lq * 16);
        float4* dst = reinterpret_cast<float4*>(&Cs[lc][lq * 16]);
        dst[0] = src[0]; dst[1] = src[1]; dst[2] = src[2]; dst[3] = src[3];
    }
    #pragma unroll
    for (int i = 0; i < 8; ++i) {
        int f = t + i * 256;
        int row = f >> 5, c4 = f & 31;
        *reinterpret_cast<float4*>(&Ws[row][c4 * 4]) =
            *reinterpret_cast<const float4*>(w1 + (size_t)row * HDIM + c4 * 4);
    }
    if (t < 64) {
        const float4* p = reinterpret_cast<const float4*>(cb + (size_t)(c0 + t) * CDIM);
        float s = 0.f;
        #pragma unroll
        for (int i = 0; i < 16; ++i) {
            float4 v = p[i];
            s = fmaf(v.x, v.x, s); s = fmaf(v.y, v.y, s);
            s = fmaf(v.z, v.z, s); s = fmaf(v.w, v.w, s);
        }
        cnorm[c0 + t] = s;
    }
    __syncthreads();
    const int tg = t >> 5, cg = t & 31;
    float acc[8][4];
    #pragma unroll
    for (int i = 0; i < 8; ++i)
        #pragma unroll
        for (int j = 0; j < 4; ++j) acc[i][j] = 0.f;
    #pragma unroll
    for (int k = 0; k < CDIM; k += 4) {
        float4 av[8];
        #pragma unroll
        for (int i = 0; i < 8; ++i)
            av[i] = *reinterpret_cast<const float4*>(&Cs[tg + 8 * i][k]);
        float4 bv[4];
        #pragma unroll
        for (int q = 0; q < 4; ++q)
            bv[q] = *reinterpret_cast<const float4*>(&Ws[k + q][cg * 4]);
        #pragma unroll
        for (int i = 0; i < 8; ++i) {
            acc[i][0] = fmaf(av[i].x, bv[0].x, acc[i][0]);
            acc[i][1] = fmaf(av[i].x, bv[0].y, acc[i][1]);
            acc[i][2] = fmaf(av[i].x, bv[0].z, acc[i][2]);
            acc[i][3] = fmaf(av[i].x, bv[0].w, acc[i][3]);
            acc[i][0] = fmaf(av[i].y, bv[1].x, acc[i][0]);
            acc[i][1] = fmaf(av[i].y, bv[1].y, acc[i][1]);
            acc[i][2] = fmaf(av[i].y, bv[1].z, acc[i][2]);
            acc[i][3] = fmaf(av[i].y, bv[1].w, acc[i][3]);
            acc[i][0] = fmaf(av[i].z, bv[2].x, acc[i][0]);
            acc[i][1] = fmaf(av[i].z, bv[2].y, acc[i][1]);
            acc[i][2] = fmaf(av[i].z, bv[2].z, acc[i][2]);
            acc[i][3] = fmaf(av[i].z, bv[2].w, acc[i][3]);
            acc[i][0] = fmaf(av[i].w, bv[3].x, acc[i][0]);
            acc[i][1] = fmaf(av[i].w, bv[3].y, acc[i][1]);
            acc[i][2] = fmaf(av[i].w, bv[3].z, acc[i][2]);
            acc[i][3] = fmaf(av[i].w, bv[3].w, acc[i][3]);
        }
    }
    float4 b1v = *reinterpret_cast<const float4*>(b1 + cg * 4);
    #pragma unroll
    for (int i = 0; i < 8; ++i) {
        float4 h;
        h.x = gelu_exact(acc[i][0] + b1v.x);
        h.y = gelu_exact(acc[i][1] + b1v.y);
        h.z = gelu_exact(acc[i][2] + b1v.z);
        h.w = gelu_exact(acc[i][3] + b1v.w);
        *reinterpret_cast<float4*>(T1 + (size_t)(c0 + tg + 8 * i) * HDIM + cg * 4) = h;
    }
}

// ---------------------------------------------------------------------------
// decoder stage 2 over codebook: table = T1 @ dec_w2 + b2   (2048 x 768)
// Grid: (2048/64, 768/128)
// ---------------------------------------------------------------------------
__global__ __launch_bounds__(256)
void dec2_kernel(const float* __restrict__ T1, const float* __restrict__ w2,
                 const float* __restrict__ b2, float* __restrict__ table)
{
    __shared__ float As[64][36];   // padded
    __shared__ float Ws[32][128];
    const int t = threadIdx.x;
    const int r0 = blockIdx.x * 64;
    const int col0 = blockIdx.y * 128;
    const int tg = t >> 5, cg = t & 31;
    float acc[8][4];
    #pragma unroll
    for (int i = 0; i < 8; ++i)
        #pragma unroll
        for (int j = 0; j < 4; ++j) acc[i][j] = 0.f;

    for (int k0 = 0; k0 < HDIM; k0 += 32) {
        __syncthreads();
        {
            int lr = t >> 2, lk = t & 3;
            const float4* src = reinterpret_cast<const float4*>(T1 + (size_t)(r0 + lr) * HDIM + k0 + lk * 8);
            float4 v0 = src[0], v1 = src[1];
            float4* dst = reinterpret_cast<float4*>(&As[lr][lk * 8]);
            dst[0] = v0; dst[1] = v1;
        }
        #pragma unroll
        for (int i = 0; i < 4; ++i) {
            int f = t + i * 256;
            int row = f >> 5, c4 = f & 31;
            *reinterpret_cast<float4*>(&Ws[row][c4 * 4]) =
                *reinterpret_cast<const float4*>(w2 + (size_t)(k0 + row) * DMODEL + col0 + c4 * 4);
        }
        __syncthreads();
        #pragma unroll
        for (int kk = 0; kk < 32; kk += 4) {
            float4 av[8];
            #pragma unroll
            for (int i = 0; i < 8; ++i)
                av[i] = *reinterpret_cast<const float4*>(&As[tg + 8 * i][kk]);
            float4 bv[4];
            #pragma unroll
            for (int q = 0; q < 4; ++q)
                bv[q] = *reinterpret_cast<const float4*>(&Ws[kk + q][cg * 4]);
            #pragma unroll
            for (int i = 0; i < 8; ++i) {
                acc[i][0] = fmaf(av[i].x, bv[0].x, acc[i][0]);
                acc[i][1] = fmaf(av[i].x, bv[0].y, acc[i][1]);
                acc[i][2] = fmaf(av[i].x, bv[0].z, acc[i][2]);
                acc[i][3] = fmaf(av[i].x, bv[0].w, acc[i][3]);
                acc[i][0] = fmaf(av[i].y, bv[1].x, acc[i][0]);
                acc[i][1] = fmaf(av[i].y, bv[1].y, acc[i][1]);
                acc[i][2] = fmaf(av[i].y, bv[1].z, acc[i][2]);
                acc[i][3] = fmaf(av[i].y, bv[1].w, acc[i][3]);
                acc[i][0] = fmaf(av[i].z, bv[2].x, acc[i][0]);
                acc[i][1] = fmaf(av[i].z, bv[2].y, acc[i][1]);
                acc[i][2] = fmaf(av[i].z, bv[2].z, acc[i][2]);
                acc[i][3] = fmaf(av[i].z, bv[2].w, acc[i][3]);
                acc[i][0] = fmaf(av[i].w, bv[3].x, acc[i][0]);
                acc[i][1] = fmaf(av[i].w, bv[3].y, acc[i][1]);
                acc[i][2] = fmaf(av[i].w, bv[3].z, acc[i][2]);
                acc[i][3] = fmaf(av[i].w, bv[3].w, acc[i][3]);
            }
        }
    }
    float4 b2v = *reinterpret_cast<const float4*>(b2 + col0 + cg * 4);
    #pragma unroll
    for (int i = 0; i < 8; ++i) {
        float4 o;
        o.x = acc[i][0] + b2v.x;
        o.y = acc[i][1] + b2v.y;
        o.z = acc[i][2] + b2v.z;
        o.w = acc[i][3] + b2v.w;
        *reinterpret_cast<float4*>(table + (size_t)(r0 + tg + 8 * i) * DMODEL + col0 + cg * 4) = o;
    }
}

// ---------------------------------------------------------------------------
// gather: x_rec[token] = table[idx[token]]; also finalizes the loss scalar
// ---------------------------------------------------------------------------
__global__ void gather_kernel(const float* __restrict__ table,
                              const int* __restrict__ idx, float* __restrict__ out,
                              const float* __restrict__ loss_accum,
                              float* __restrict__ loss_out)
{
    if (blockIdx.x == 0 && threadIdx.x == 0) {
        loss_out[0] = loss_accum[0] * (1.25f / 4194304.0f);
    }
    const int F = TOKENS * (DMODEL / 4);
    const float4* tab4 = reinterpret_cast<const float4*>(table);
    float4* out4 = reinterpret_cast<float4*>(out);
    for (int f = blockIdx.x * blockDim.x + threadIdx.x; f < F;
         f += gridDim.x * blockDim.x) {
        int token = f / 192;
        int j = f - token * 192;
        out4[f] = tab4[(size_t)idx[token] * 192 + j];
    }
}

// ---------------------------------------------------------------------------
extern "C" void kernel_launch(void* const* d_in, const int* in_sizes, int n_in,
                              void* d_out, int out_size, void* d_ws, size_t ws_size,
                              hipStream_t stream)
{
    const float* x      = (const float*)d_in[0];
    const float* enc_w1 = (const float*)d_in[1];
    const float* enc_b1 = (const float*)d_in[2];
    const float* enc_w2 = (const float*)d_in[3];
    const float* enc_b2 = (const float*)d_in[4];
    const float* cb     = (const float*)d_in[5];
    const float* dec_w1 = (const float*)d_in[6];
    const float* dec_b1 = (const float*)d_in[7];
    const float* dec_w2 = (const float*)d_in[8];
    const float* dec_b2 = (const float*)d_in[9];

    float* out     = (float*)d_out;
    float* xrec    = out;                                   // 65536*768
    float* idxf    = out + (size_t)TOKENS * DMODEL;         // 65536
    float* lossout = idxf + TOKENS;                         // 1

    float* ws    = (float*)d_ws;
    float* Z     = ws;                                      // 4,194,304 floats
    float* T1    = Z + (size_t)TOKENS * CDIM;               // 262,144
    float* table = T1 + (size_t)NCODE * HDIM;               // 1,572,864
    float* cnorm = table + (size_t)NCODE * DMODEL;          // 2,048
    int*   idx   = (int*)(cnorm + NCODE);                   // 65,536
    float* lacc  = (float*)(idx + TOKENS);                  // 1

    hipMemsetAsync(lacc, 0, sizeof(float), stream);

    enc_fused<<<TOKENS / 64, 256, 0, stream>>>(x, enc_w1, enc_b1, enc_w2, enc_b2, Z);
    dec1_kernel<<<NCODE / 64, 256, 0, stream>>>(cb, dec_w1, dec_b1, T1, cnorm);
    dec2_kernel<<<dim3(NCODE / 64, DMODEL / 128), 256, 0, stream>>>(T1, dec_w2, dec_b2, table);
    vq_kernel<<<TOKENS / 64, 256, 0, stream>>>(Z, cb, cnorm, idx, idxf, lacc);
    gather_kernel<<<2048, 256, 0, stream>>>(table, idx, xrec, lacc, lossout);
}

// Round 8
// 844.471 us; speedup vs baseline: 1.1659x; 1.1659x over previous
//
#include <hip/hip_runtime.h>
#include <math.h>

#define TOKENS 65536
#define DMODEL 768
#define HDIM 128
#define CDIM 64
#define NCODE 2048

__device__ __forceinline__ float gelu_exact(float v) {
    return 0.5f * v * (1.0f + erff(v * 0.7071067811865476f));
}

__device__ __forceinline__ void load_lds16(const float* g, float* l) {
    __builtin_amdgcn_global_load_lds(
        (const __attribute__((address_space(1))) void*)g,
        (__attribute__((address_space(3))) void*)l, 16, 0, 0);
}

// ---------------------------------------------------------------------------
// Fused encoder: Z = GELU(X @ W1 + b1) @ W2 + b2
// 64 tokens/block, 256 threads.
// Thread -> rows tg*8+i (CONSECUTIVE): the 8 ds_read_b128 per kk-step hit 8
// distinct bank quads (stride 36: quad = (32tg+4i+kk)%32). The old tg+8*i
// mapping put all 8 reads on ONE quad (8*stride = 0 mod 32) -> the 7.6e7
// cross-instruction conflicts of r2-r5 (bit-identical across layout changes).
// X: reg-staged into padded Xs[2][64][36] (T14 split: load early, ds_write
// after barrier). W1: gload_lds double-buffer pipeline (r6, conflict-free).
// LDS 51.2KB -> 3 blocks/CU = 3 waves/EU; launch_bounds(256,3) gives the
// allocator a ~170-VGPR budget (amdgpu_waves_per_eu(4,4) was NOT honored in
// r4-r6: VGPR_Count pinned at 64 -> scratch spill whenever demand > 64).
// ---------------------------------------------------------------------------
__global__ __launch_bounds__(256, 3)
void enc_fused(const float* __restrict__ x, const float* __restrict__ w1,
               const float* __restrict__ b1, const float* __restrict__ w2,
               const float* __restrict__ b2, float* __restrict__ Z)
{
    __shared__ union {
        struct { float Xs[2][64][36]; float Ws[2][32][128]; } a;  // 51200 B
        float H1s[64][132];                                       // 33792 B
    } u;

    const int t = threadIdx.x;
    const int w = t >> 6, l = t & 63;
    const size_t tok0 = (size_t)blockIdx.x * 64;
    const int tg = t >> 5;   // 0..7; rows tg*8 .. tg*8+7 (consecutive!)
    const int cg = t & 31;   // cols cg*4 .. cg*4+3

    float acc[8][4];
    #pragma unroll
    for (int i = 0; i < 8; ++i)
        #pragma unroll
        for (int j = 0; j < 4; ++j) acc[i][j] = 0.f;

    // W1 staging (lane-linear gload_lds into [32][128])
    const int wrow_ = l >> 5;
    const int wcol_ = 4 * (l & 31);
    #define STAGE_W(buf, k0s)                                              \
        {                                                                  \
            float* dst = &u.a.Ws[buf][0][0];                               \
            _Pragma("unroll")                                              \
            for (int j = 0; j < 4; ++j) {                                  \
                const int chunk = w * 4 + j;                               \
                const int row = chunk * 2 + wrow_;                         \
                load_lds16(w1 + (size_t)((k0s) + row) * HDIM + wcol_,      \
                           dst + chunk * 256);                             \
            }                                                              \
        }

    // X staging coords: thread loads row ltok, cols lkg*8..lkg*8+7
    const int ltok = t >> 2, lkg = t & 3;
    const float* xrow = x + (tok0 + ltok) * DMODEL + lkg * 8;

    // prologue: X(0) -> regs -> LDS buf0; W(0) staged; X(1) -> regs
    float4 xr0, xr1;
    {
        const float4* s = reinterpret_cast<const float4*>(xrow);
        xr0 = s[0]; xr1 = s[1];
    }
    *reinterpret_cast<float4*>(&u.a.Xs[0][ltok][lkg * 8]) = xr0;
    *reinterpret_cast<float4*>(&u.a.Xs[0][ltok][lkg * 8 + 4]) = xr1;
    STAGE_W(0, 0);
    {
        const float4* s = reinterpret_cast<const float4*>(xrow + 32);
        xr0 = s[0]; xr1 = s[1];
    }
    __syncthreads();   // drains W(0) vmcnt; X(1) regs also complete

    for (int tile = 0; tile < 24; ++tile) {
        const int cur = tile & 1;
        if (tile + 1 < 24) {
            // X(tile+1): regs (complete at last barrier) -> LDS nxt buffer
            *reinterpret_cast<float4*>(&u.a.Xs[cur ^ 1][ltok][lkg * 8]) = xr0;
            *reinterpret_cast<float4*>(&u.a.Xs[cur ^ 1][ltok][lkg * 8 + 4]) = xr1;
            STAGE_W(cur ^ 1, (tile + 1) * 32);       // async across compute
            if (tile + 2 < 24) {
                const float4* s = reinterpret_cast<const float4*>(xrow + (tile + 2) * 32);
                xr0 = s[0]; xr1 = s[1];              // in flight across compute
            }
        }
        const float(*Xc)[36] = u.a.Xs[cur];
        const float(*Wc)[128] = u.a.Ws[cur];
        #pragma unroll
        for (int kk = 0; kk < 32; kk += 4) {
            float4 av[8];
            #pragma unroll
            for (int i = 0; i < 8; ++i)
                av[i] = *reinterpret_cast<const float4*>(&Xc[tg * 8 + i][kk]);
            float4 bv[4];
            #pragma unroll
            for (int q = 0; q < 4; ++q)
                bv[q] = *reinterpret_cast<const float4*>(&Wc[kk + q][cg * 4]);
            #pragma unroll
            for (int i = 0; i < 8; ++i) {
                acc[i][0] = fmaf(av[i].x, bv[0].x, acc[i][0]);
                acc[i][1] = fmaf(av[i].x, bv[0].y, acc[i][1]);
                acc[i][2] = fmaf(av[i].x, bv[0].z, acc[i][2]);
                acc[i][3] = fmaf(av[i].x, bv[0].w, acc[i][3]);
                acc[i][0] = fmaf(av[i].y, bv[1].x, acc[i][0]);
                acc[i][1] = fmaf(av[i].y, bv[1].y, acc[i][1]);
                acc[i][2] = fmaf(av[i].y, bv[1].z, acc[i][2]);
                acc[i][3] = fmaf(av[i].y, bv[1].w, acc[i][3]);
                acc[i][0] = fmaf(av[i].z, bv[2].x, acc[i][0]);
                acc[i][1] = fmaf(av[i].z, bv[2].y, acc[i][1]);
                acc[i][2] = fmaf(av[i].z, bv[2].z, acc[i][2]);
                acc[i][3] = fmaf(av[i].z, bv[2].w, acc[i][3]);
                acc[i][0] = fmaf(av[i].w, bv[3].x, acc[i][0]);
                acc[i][1] = fmaf(av[i].w, bv[3].y, acc[i][1]);
                acc[i][2] = fmaf(av[i].w, bv[3].z, acc[i][2]);
                acc[i][3] = fmaf(av[i].w, bv[3].w, acc[i][3]);
            }
        }
        __syncthreads();   // readers done; drains W(nxt) + X regs loads
    }

    // bias + GELU -> H1s (overlays dead phase-1 region; barrier above covers)
    {
        float4 b1v = *reinterpret_cast<const float4*>(b1 + cg * 4);
        #pragma unroll
        for (int i = 0; i < 8; ++i) {
            float4 h;
            h.x = gelu_exact(acc[i][0] + b1v.x);
            h.y = gelu_exact(acc[i][1] + b1v.y);
            h.z = gelu_exact(acc[i][2] + b1v.z);
            h.w = gelu_exact(acc[i][3] + b1v.w);
            *reinterpret_cast<float4*>(&u.H1s[tg * 8 + i][cg * 4]) = h;
        }
    }
    __syncthreads();

    // phase B: Z = H1 @ W2 + b2 ; W2 from global (32 KB, L2-hot)
    const int tg2 = t >> 4;   // rows tg2*4 .. +3 (consecutive)
    const int cg2 = t & 15;
    const float4* w2_4 = reinterpret_cast<const float4*>(w2);
    float accB[4][4];
    #pragma unroll
    for (int i = 0; i < 4; ++i)
        #pragma unroll
        for (int j = 0; j < 4; ++j) accB[i][j] = 0.f;

    float4 bvn[4];
    #pragma unroll
    for (int q = 0; q < 4; ++q) bvn[q] = w2_4[(size_t)q * 16 + cg2];

    for (int k = 0; k < HDIM; k += 4) {
        float4 bv[4];
        #pragma unroll
        for (int q = 0; q < 4; ++q) bv[q] = bvn[q];
        if (k + 4 < HDIM) {
            #pragma unroll
            for (int q = 0; q < 4; ++q)
                bvn[q] = w2_4[(size_t)(k + 4 + q) * 16 + cg2];
        }
        float4 av[4];
        #pragma unroll
        for (int i = 0; i < 4; ++i)
            av[i] = *reinterpret_cast<const float4*>(&u.H1s[tg2 * 4 + i][k]);
        #pragma unroll
        for (int i = 0; i < 4; ++i) {
            accB[i][0] = fmaf(av[i].x, bv[0].x, accB[i][0]);
            accB[i][1] = fmaf(av[i].x, bv[0].y, accB[i][1]);
            accB[i][2] = fmaf(av[i].x, bv[0].z, accB[i][2]);
            accB[i][3] = fmaf(av[i].x, bv[0].w, accB[i][3]);
            accB[i][0] = fmaf(av[i].y, bv[1].x, accB[i][0]);
            accB[i][1] = fmaf(av[i].y, bv[1].y, accB[i][1]);
            accB[i][2] = fmaf(av[i].y, bv[1].z, accB[i][2]);
            accB[i][3] = fmaf(av[i].y, bv[1].w, accB[i][3]);
            accB[i][0] = fmaf(av[i].z, bv[2].x, accB[i][0]);
            accB[i][1] = fmaf(av[i].z, bv[2].y, accB[i][1]);
            accB[i][2] = fmaf(av[i].z, bv[2].z, accB[i][2]);
            accB[i][3] = fmaf(av[i].z, bv[2].w, accB[i][3]);
            accB[i][0] = fmaf(av[i].w, bv[3].x, accB[i][0]);
            accB[i][1] = fmaf(av[i].w, bv[3].y, accB[i][1]);
            accB[i][2] = fmaf(av[i].w, bv[3].z, accB[i][2]);
            accB[i][3] = fmaf(av[i].w, bv[3].w, accB[i][3]);
        }
    }
    {
        float4 b2v = *reinterpret_cast<const float4*>(b2 + cg2 * 4);
        #pragma unroll
        for (int i = 0; i < 4; ++i) {
            float4 o;
            o.x = accB[i][0] + b2v.x;
            o.y = accB[i][1] + b2v.y;
            o.z = accB[i][2] + b2v.z;
            o.w = accB[i][3] + b2v.w;
            *reinterpret_cast<float4*>(Z + (tok0 + tg2 * 4 + i) * CDIM + cg2 * 4) = o;
        }
    }
    #undef STAGE_W
}

// ---------------------------------------------------------------------------
// VQ: argmin over 2048 codes + loss. Rows tg*8+i (consecutive — same
// bank-quad-spread fix as enc; Zs stride 68 = 4 mod 32).
// ---------------------------------------------------------------------------
__global__ __launch_bounds__(256)
void vq_kernel(const float* __restrict__ Z, const float* __restrict__ cb,
               const float* __restrict__ cnorm, int* __restrict__ idx_out,
               float* __restrict__ idxf_out, float* __restrict__ loss_accum)
{
    __shared__ float Zs[64][68];     // 17.4 KB
    __shared__ float CsT[64][128];   // 32 KB, [k][code]
    __shared__ float tgsum[8];

    const int t = threadIdx.x;
    const size_t tok0 = (size_t)blockIdx.x * 64;
    const int tg = t >> 5, cg = t & 31;
    const int lc = t >> 1, lh = t & 1;

    {
        int ltok = t >> 2, lq = t & 3;
        const float4* src = reinterpret_cast<const float4*>(Z + (tok0 + ltok) * CDIM + lq * 16);
        float4* dst = reinterpret_cast<float4*>(&Zs[ltok][lq * 16]);
        dst[0] = src[0]; dst[1] = src[1]; dst[2] = src[2]; dst[3] = src[3];
    }
    float4 cv[8];
    {
        const float4* src = reinterpret_cast<const float4*>(cb + (size_t)lc * CDIM + lh * 32);
        #pragma unroll
        for (int i = 0; i < 8; ++i) cv[i] = src[i];
    }
    __syncthreads();

    // znorm for rows tg*8+i, butterfly over the 32-lane half-wave
    float zn[8];
    {
        #pragma unroll
        for (int i = 0; i < 8; ++i) {
            float a = Zs[tg * 8 + i][cg * 2];
            float b = Zs[tg * 8 + i][cg * 2 + 1];
            zn[i] = fmaf(a, a, b * b);
        }
        #pragma unroll
        for (int m = 16; m >= 1; m >>= 1)
            #pragma unroll
            for (int i = 0; i < 8; ++i) zn[i] += __shfl_xor(zn[i], m, 32);
    }

    float minv[8]; int mini[8];
    #pragma unroll
    for (int i = 0; i < 8; ++i) { minv[i] = INFINITY; mini[i] = 0; }

    for (int tile = 0; tile < 16; ++tile) {
        const int code0 = tile * 128;
        __syncthreads();
        #pragma unroll
        for (int i = 0; i < 8; ++i) {
            int k = lh * 32 + i * 4;
            CsT[k + 0][lc] = cv[i].x;
            CsT[k + 1][lc] = cv[i].y;
            CsT[k + 2][lc] = cv[i].z;
            CsT[k + 3][lc] = cv[i].w;
        }
        __syncthreads();
        if (tile + 1 < 16) {
            const float4* src = reinterpret_cast<const float4*>(
                cb + (size_t)(code0 + 128 + lc) * CDIM + lh * 32);
            #pragma unroll
            for (int i = 0; i < 8; ++i) cv[i] = src[i];
        }

        float dot[8][4];
        #pragma unroll
        for (int i = 0; i < 8; ++i)
            #pragma unroll
            for (int j = 0; j < 4; ++j) dot[i][j] = 0.f;

        #pragma unroll
        for (int k = 0; k < CDIM; k += 4) {
            float4 av[8];
            #pragma unroll
            for (int i = 0; i < 8; ++i)
                av[i] = *reinterpret_cast<const float4*>(&Zs[tg * 8 + i][k]);
            float4 bv[4];
            #pragma unroll
            for (int q = 0; q < 4; ++q)
                bv[q] = *reinterpret_cast<const float4*>(&CsT[k + q][cg * 4]);
            #pragma unroll
            for (int i = 0; i < 8; ++i) {
                dot[i][0] = fmaf(av[i].x, bv[0].x, dot[i][0]);
                dot[i][1] = fmaf(av[i].x, bv[0].y, dot[i][1]);
                dot[i][2] = fmaf(av[i].x, bv[0].z, dot[i][2]);
                dot[i][3] = fmaf(av[i].x, bv[0].w, dot[i][3]);
                dot[i][0] = fmaf(av[i].y, bv[1].x, dot[i][0]);
                dot[i][1] = fmaf(av[i].y, bv[1].y, dot[i][1]);
                dot[i][2] = fmaf(av[i].y, bv[1].z, dot[i][2]);
                dot[i][3] = fmaf(av[i].y, bv[1].w, dot[i][3]);
                dot[i][0] = fmaf(av[i].z, bv[2].x, dot[i][0]);
                dot[i][1] = fmaf(av[i].z, bv[2].y, dot[i][1]);
                dot[i][2] = fmaf(av[i].z, bv[2].z, dot[i][2]);
                dot[i][3] = fmaf(av[i].z, bv[2].w, dot[i][3]);
                dot[i][0] = fmaf(av[i].w, bv[3].x, dot[i][0]);
                dot[i][1] = fmaf(av[i].w, bv[3].y, dot[i][1]);
                dot[i][2] = fmaf(av[i].w, bv[3].z, dot[i][2]);
                dot[i][3] = fmaf(av[i].w, bv[3].w, dot[i][3]);
            }
        }
        #pragma unroll
        for (int j = 0; j < 4; ++j) {
            int ci = code0 + cg * 4 + j;
            float cn = cnorm[ci];
            #pragma unroll
            for (int i = 0; i < 8; ++i) {
                float s = (zn[i] + cn) - 2.f * dot[i][j];
                if (s < minv[i]) { minv[i] = s; mini[i] = ci; }
            }
        }
    }

    #pragma unroll
    for (int i = 0; i < 8; ++i) {
        float v = minv[i]; int ci = mini[i];
        #pragma unroll
        for (int m = 16; m >= 1; m >>= 1) {
            float ov = __shfl_xor(v, m, 32);
            int oi = __shfl_xor(ci, m, 32);
            if (ov < v || (ov == v && oi < ci)) { v = ov; ci = oi; }
        }
        minv[i] = v; mini[i] = ci;
    }

    if (cg == 0) {
        float s = 0.f;
        #pragma unroll
        for (int i = 0; i < 8; ++i) {
            size_t tok = tok0 + tg * 8 + i;
            idx_out[tok] = mini[i];
            idxf_out[tok] = (float)mini[i];
            s += minv[i];
        }
        tgsum[tg] = s;
    }
    __syncthreads();
    if (t == 0) {
        float s = 0.f;
        #pragma unroll
        for (int i = 0; i < 8; ++i) s += tgsum[i];
        atomicAdd(loss_accum, s);
    }
}

// ---------------------------------------------------------------------------
// decoder stage 1: T1 = GELU(cb @ dec_w1 + b1) (2048x128) + fused cnorm
// ---------------------------------------------------------------------------
__global__ __launch_bounds__(256)
void dec1_kernel(const float* __restrict__ cb, const float* __restrict__ w1,
                 const float* __restrict__ b1, float* __restrict__ T1,
                 float* __restrict__ cnorm)
{
    __shared__ float Cs[64][68];
    __shared__ float Ws[64][128];

    const int t = threadIdx.x;
    const int c0 = blockIdx.x * 64;
    {
        int lc = t >> 2, lq = t & 3;
        const float4* src = reinterpret_cast<const float4*>(cb + (size_t)(c0 + lc) * CDIM + lq * 16);
        float4* dst = reinterpret_cast<float4*>(&Cs[lc][lq * 16]);
        dst[0] = src[0]; dst[1] = src[1]; dst[2] = src[2]; dst[3] = src[3];
    }
    #pragma unroll
    for (int i = 0; i < 8; ++i) {
        int f = t + i * 256;
        int row = f >> 5, c4 = f & 31;
        *reinterpret_cast<float4*>(&Ws[row][c4 * 4]) =
            *reinterpret_cast<const float4*>(w1 + (size_t)row * HDIM + c4 * 4);
    }
    if (t < 64) {
        const float4* p = reinterpret_cast<const float4*>(cb + (size_t)(c0 + t) * CDIM);
        float s = 0.f;
        #pragma unroll
        for (int i = 0; i < 16; ++i) {
            float4 v = p[i];
            s = fmaf(v.x, v.x, s); s = fmaf(v.y, v.y, s);
            s = fmaf(v.z, v.z, s); s = fmaf(v.w, v.w, s);
        }
        cnorm[c0 + t] = s;
    }
    __syncthreads();
    const int tg = t >> 5, cg = t & 31;
    float acc[8][4];
    #pragma unroll
    for (int i = 0; i < 8; ++i)
        #pragma unroll
        for (int j = 0; j < 4; ++j) acc[i][j] = 0.f;
    #pragma unroll
    for (int k = 0; k < CDIM; k += 4) {
        float4 av[8];
        #pragma unroll
        for (int i = 0; i < 8; ++i)
            av[i] = *reinterpret_cast<const float4*>(&Cs[tg * 8 + i][k]);
        float4 bv[4];
        #pragma unroll
        for (int q = 0; q < 4; ++q)
            bv[q] = *reinterpret_cast<const float4*>(&Ws[k + q][cg * 4]);
        #pragma unroll
        for (int i = 0; i < 8; ++i) {
            acc[i][0] = fmaf(av[i].x, bv[0].x, acc[i][0]);
            acc[i][1] = fmaf(av[i].x, bv[0].y, acc[i][1]);
            acc[i][2] = fmaf(av[i].x, bv[0].z, acc[i][2]);
            acc[i][3] = fmaf(av[i].x, bv[0].w, acc[i][3]);
            acc[i][0] = fmaf(av[i].y, bv[1].x, acc[i][0]);
            acc[i][1] = fmaf(av[i].y, bv[1].y, acc[i][1]);
            acc[i][2] = fmaf(av[i].y, bv[1].z, acc[i][2]);
            acc[i][3] = fmaf(av[i].y, bv[1].w, acc[i][3]);
            acc[i][0] = fmaf(av[i].z, bv[2].x, acc[i][0]);
            acc[i][1] = fmaf(av[i].z, bv[2].y, acc[i][1]);
            acc[i][2] = fmaf(av[i].z, bv[2].z, acc[i][2]);
            acc[i][3] = fmaf(av[i].z, bv[2].w, acc[i][3]);
            acc[i][0] = fmaf(av[i].w, bv[3].x, acc[i][0]);
            acc[i][1] = fmaf(av[i].w, bv[3].y, acc[i][1]);
            acc[i][2] = fmaf(av[i].w, bv[3].z, acc[i][2]);
            acc[i][3] = fmaf(av[i].w, bv[3].w, acc[i][3]);
        }
    }
    float4 b1v = *reinterpret_cast<const float4*>(b1 + cg * 4);
    #pragma unroll
    for (int i = 0; i < 8; ++i) {
        float4 h;
        h.x = gelu_exact(acc[i][0] + b1v.x);
        h.y = gelu_exact(acc[i][1] + b1v.y);
        h.z = gelu_exact(acc[i][2] + b1v.z);
        h.w = gelu_exact(acc[i][3] + b1v.w);
        *reinterpret_cast<float4*>(T1 + (size_t)(c0 + tg * 8 + i) * HDIM + cg * 4) = h;
    }
}

// ---------------------------------------------------------------------------
// decoder stage 2: table = T1 @ dec_w2 + b2   (2048 x 768)
// ---------------------------------------------------------------------------
__global__ __launch_bounds__(256)
void dec2_kernel(const float* __restrict__ T1, const float* __restrict__ w2,
                 const float* __restrict__ b2, float* __restrict__ table)
{
    __shared__ float As[64][36];
    __shared__ float Ws[32][128];
    const int t = threadIdx.x;
    const int r0 = blockIdx.x * 64;
    const int col0 = blockIdx.y * 128;
    const int tg = t >> 5, cg = t & 31;
    float acc[8][4];
    #pragma unroll
    for (int i = 0; i < 8; ++i)
        #pragma unroll
        for (int j = 0; j < 4; ++j) acc[i][j] = 0.f;

    for (int k0 = 0; k0 < HDIM; k0 += 32) {
        __syncthreads();
        {
            int lr = t >> 2, lk = t & 3;
            const float4* src = reinterpret_cast<const float4*>(T1 + (size_t)(r0 + lr) * HDIM + k0 + lk * 8);
            float4 v0 = src[0], v1 = src[1];
            float4* dst = reinterpret_cast<float4*>(&As[lr][lk * 8]);
            dst[0] = v0; dst[1] = v1;
        }
        #pragma unroll
        for (int i = 0; i < 4; ++i) {
            int f = t + i * 256;
            int row = f >> 5, c4 = f & 31;
            *reinterpret_cast<float4*>(&Ws[row][c4 * 4]) =
                *reinterpret_cast<const float4*>(w2 + (size_t)(k0 + row) * DMODEL + col0 + c4 * 4);
        }
        __syncthreads();
        #pragma unroll
        for (int kk = 0; kk < 32; kk += 4) {
            float4 av[8];
            #pragma unroll
            for (int i = 0; i < 8; ++i)
                av[i] = *reinterpret_cast<const float4*>(&As[tg * 8 + i][kk]);
            float4 bv[4];
            #pragma unroll
            for (int q = 0; q < 4; ++q)
                bv[q] = *reinterpret_cast<const float4*>(&Ws[kk + q][cg * 4]);
            #pragma unroll
            for (int i = 0; i < 8; ++i) {
                acc[i][0] = fmaf(av[i].x, bv[0].x, acc[i][0]);
                acc[i][1] = fmaf(av[i].x, bv[0].y, acc[i][1]);
                acc[i][2] = fmaf(av[i].x, bv[0].z, acc[i][2]);
                acc[i][3] = fmaf(av[i].x, bv[0].w, acc[i][3]);
                acc[i][0] = fmaf(av[i].y, bv[1].x, acc[i][0]);
                acc[i][1] = fmaf(av[i].y, bv[1].y, acc[i][1]);
                acc[i][2] = fmaf(av[i].y, bv[1].z, acc[i][2]);
                acc[i][3] = fmaf(av[i].y, bv[1].w, acc[i][3]);
                acc[i][0] = fmaf(av[i].z, bv[2].x, acc[i][0]);
                acc[i][1] = fmaf(av[i].z, bv[2].y, acc[i][1]);
                acc[i][2] = fmaf(av[i].z, bv[2].z, acc[i][2]);
                acc[i][3] = fmaf(av[i].z, bv[2].w, acc[i][3]);
                acc[i][0] = fmaf(av[i].w, bv[3].x, acc[i][0]);
                acc[i][1] = fmaf(av[i].w, bv[3].y, acc[i][1]);
                acc[i][2] = fmaf(av[i].w, bv[3].z, acc[i][2]);
                acc[i][3] = fmaf(av[i].w, bv[3].w, acc[i][3]);
            }
        }
    }
    float4 b2v = *reinterpret_cast<const float4*>(b2 + col0 + cg * 4);
    #pragma unroll
    for (int i = 0; i < 8; ++i) {
        float4 o;
        o.x = acc[i][0] + b2v.x;
        o.y = acc[i][1] + b2v.y;
        o.z = acc[i][2] + b2v.z;
        o.w = acc[i][3] + b2v.w;
        *reinterpret_cast<float4*>(table + (size_t)(r0 + tg * 8 + i) * DMODEL + col0 + cg * 4) = o;
    }
}

// ---------------------------------------------------------------------------
// gather: x_rec[token] = table[idx[token]]; finalizes the loss scalar
// ---------------------------------------------------------------------------
__global__ void gather_kernel(const float* __restrict__ table,
                              const int* __restrict__ idx, float* __restrict__ out,
                              const float* __restrict__ loss_accum,
                              float* __restrict__ loss_out)
{
    if (blockIdx.x == 0 && threadIdx.x == 0) {
        loss_out[0] = loss_accum[0] * (1.25f / 4194304.0f);
    }
    const int F = TOKENS * (DMODEL / 4);
    const float4* tab4 = reinterpret_cast<const float4*>(table);
    float4* out4 = reinterpret_cast<float4*>(out);
    for (int f = blockIdx.x * blockDim.x + threadIdx.x; f < F;
         f += gridDim.x * blockDim.x) {
        int token = f / 192;
        int j = f - token * 192;
        out4[f] = tab4[(size_t)idx[token] * 192 + j];
    }
}

// ---------------------------------------------------------------------------
extern "C" void kernel_launch(void* const* d_in, const int* in_sizes, int n_in,
                              void* d_out, int out_size, void* d_ws, size_t ws_size,
                              hipStream_t stream)
{
    const float* x      = (const float*)d_in[0];
    const float* enc_w1 = (const float*)d_in[1];
    const float* enc_b1 = (const float*)d_in[2];
    const float* enc_w2 = (const float*)d_in[3];
    const float* enc_b2 = (const float*)d_in[4];
    const float* cb     = (const float*)d_in[5];
    const float* dec_w1 = (const float*)d_in[6];
    const float* dec_b1 = (const float*)d_in[7];
    const float* dec_w2 = (const float*)d_in[8];
    const float* dec_b2 = (const float*)d_in[9];

    float* out     = (float*)d_out;
    float* xrec    = out;
    float* idxf    = out + (size_t)TOKENS * DMODEL;
    float* lossout = idxf + TOKENS;

    float* ws    = (float*)d_ws;
    float* Z     = ws;
    float* T1    = Z + (size_t)TOKENS * CDIM;
    float* table = T1 + (size_t)NCODE * HDIM;
    float* cnorm = table + (size_t)NCODE * DMODEL;
    int*   idx   = (int*)(cnorm + NCODE);
    float* lacc  = (float*)(idx + TOKENS);

    hipMemsetAsync(lacc, 0, sizeof(float), stream);

    enc_fused<<<TOKENS / 64, 256, 0, stream>>>(x, enc_w1, enc_b1, enc_w2, enc_b2, Z);
    dec1_kernel<<<NCODE / 64, 256, 0, stream>>>(cb, dec_w1, dec_b1, T1, cnorm);
    dec2_kernel<<<dim3(NCODE / 64, DMODEL / 128), 256, 0, stream>>>(T1, dec_w2, dec_b2, table);
    vq_kernel<<<TOKENS / 64, 256, 0, stream>>>(Z, cb, cnorm, idx, idxf, lacc);
    gather_kernel<<<2048, 256, 0, stream>>>(table, idx, xrec, lacc, lossout);
}